// Round 1
// baseline (889.035 us; speedup 1.0000x reference)
//
#include <hip/hip_runtime.h>
#include <hip/hip_bf16.h>

#define NB 8
#define C1 256
#define C2 512
#define NSP 3136   // 56*56

typedef __attribute__((ext_vector_type(8))) short bf16x8;
typedef __attribute__((ext_vector_type(4))) float f32x4;

__device__ __forceinline__ ushort f2b(float f) {
  __hip_bfloat16 h = __float2bfloat16(f);
  return *reinterpret_cast<ushort*>(&h);
}

// ---------------- K0: Wt[c][o] = W[o][c] (f32, 512x256) ----------------
__global__ void k_wt(const float* __restrict__ W, float* __restrict__ Wt) {
  int c = blockIdx.x;   // 512
  int o = threadIdx.x;  // 256
  Wt[(size_t)c * C1 + o] = W[(size_t)o * C2 + c];
}

// ---------------- K1: x1t[b][n][c] = bf16(x1[b][c][n]) ----------------
__global__ __launch_bounds__(256) void k_x1t(const float* __restrict__ x1,
                                             ushort* __restrict__ x1t) {
  __shared__ float t[32][33];
  int b = blockIdx.z;
  int n0 = blockIdx.x * 32;
  int c0 = blockIdx.y * 32;
  int tid = threadIdx.x;
  int r = tid >> 3, q = (tid & 7) * 4;
  const float* src = x1 + ((size_t)b * C1 + (c0 + r)) * NSP + n0 + q;
  float4 v = *reinterpret_cast<const float4*>(src);
  t[r][q] = v.x; t[r][q + 1] = v.y; t[r][q + 2] = v.z; t[r][q + 3] = v.w;
  __syncthreads();
  // write: n = n0+r, c = c0+q..q+3
  ushort4 o;
  o.x = f2b(t[q + 0][r]); o.y = f2b(t[q + 1][r]);
  o.z = f2b(t[q + 2][r]); o.w = f2b(t[q + 3][r]);
  *reinterpret_cast<ushort4*>(x1t + ((size_t)b * NSP + n0 + r) * C1 + c0 + q) = o;
}

// ---------------- K2: projection x2p = W@x2 + b, bf16 in two layouts ----
// cm[b][o][n]  (n contiguous)   mc[b][n][o]  (o contiguous)
__global__ __launch_bounds__(256) void k_proj(const float* __restrict__ Wt,
    const float* __restrict__ x2, const float* __restrict__ bias,
    ushort* __restrict__ cm, ushort* __restrict__ mc) {
  int bid = blockIdx.x;          // 8*49
  int b = bid & 7;
  int nc = bid >> 3;             // 0..48
  int tid = threadIdx.x;
  int n = nc * 64 + (tid & 63);
  int o0 = __builtin_amdgcn_readfirstlane((tid >> 6) << 6);  // wave-uniform
  float acc[64];
#pragma unroll
  for (int i = 0; i < 64; i++) acc[i] = 0.f;
  const float* xp = x2 + (size_t)b * C2 * NSP + n;
  const float* wp = Wt + o0;
  for (int c = 0; c < C2; c++) {
    float v = xp[(size_t)c * NSP];
    const float* wr = wp + c * C1;   // uniform address -> s_loads
#pragma unroll
    for (int i = 0; i < 64; i++) acc[i] = fmaf(wr[i], v, acc[i]);
  }
#pragma unroll
  for (int i = 0; i < 64; i++) acc[i] += bias[o0 + i];
  size_t cmb = ((size_t)b * C1 + o0) * NSP + n;
#pragma unroll
  for (int i = 0; i < 64; i++) cm[cmb + (size_t)i * NSP] = f2b(acc[i]);
  ushort* mrow = mc + ((size_t)b * NSP + n) * C1 + o0;
#pragma unroll
  for (int i = 0; i < 64; i += 4) {
    ushort4 p;
    p.x = f2b(acc[i]); p.y = f2b(acc[i + 1]);
    p.z = f2b(acc[i + 2]); p.w = f2b(acc[i + 3]);
    *reinterpret_cast<ushort4*>(mrow + i) = p;
  }
}

// ---------------- K3: flash attention (score = -energy) ----------------
// x1t: Q bf16 [b][n][c]; mc: K^T bf16 [b][m][c]; cm: V bf16 [b][c][m]
// out[b][c][n] = gamma * (softmax_m(-Q.K) @ V^T)[n][c] + x1[b][c][n]
__global__ __launch_bounds__(128) void k_attn(
    const ushort* __restrict__ x1t, const ushort* __restrict__ cm,
    const ushort* __restrict__ mc, const float* __restrict__ x1,
    const float* __restrict__ gamma, float* __restrict__ out) {
  __shared__ __align__(16) ushort Plds[2][16][40];  // per-wave P tile, padded rows
  int bid = blockIdx.x;   // 8*98
  int b = bid & 7;        // batch <-> XCD for L2 locality
  int nt = bid >> 3;      // 0..97
  int tid = threadIdx.x;
  int w = tid >> 6;
  int lane = tid & 63;
  int l15 = lane & 15;
  int g = lane >> 4;
  int n0 = nt * 32 + w * 16;
  float gm = gamma[0];

  // hoist Q fragments: A-layout row=l15 (n), k = cc*32 + g*8 + i (c)
  bf16x8 qf[8];
  const ushort* qb = x1t + ((size_t)b * NSP + n0 + l15) * C1 + g * 8;
#pragma unroll
  for (int cc = 0; cc < 8; cc++)
    qf[cc] = *reinterpret_cast<const bf16x8*>(qb + cc * 32);

  f32x4 zero = {0.f, 0.f, 0.f, 0.f};
  f32x4 O[16];
#pragma unroll
  for (int i = 0; i < 16; i++) O[i] = zero;
  float M[4], L[4];
#pragma unroll
  for (int r = 0; r < 4; r++) { M[r] = -3.0e38f; L[r] = 0.f; }

  const ushort* mcb = mc + (size_t)b * NSP * C1 + (size_t)g * 8;
  const ushort* cmb = cm + (size_t)b * C1 * NSP + (size_t)g * 8;

  for (int m0 = 0; m0 < NSP; m0 += 32) {
    // ---- S = Q.K for 16n x 32m (split-K accumulators for ILP) ----
    f32x4 s0a = zero, s0b = zero, s1a = zero, s1b = zero;
    const ushort* kb0 = mcb + (size_t)(m0 + l15) * C1;
    const ushort* kb1 = mcb + (size_t)(m0 + 16 + l15) * C1;
#pragma unroll
    for (int cc = 0; cc < 8; cc += 2) {
      bf16x8 k0 = *reinterpret_cast<const bf16x8*>(kb0 + cc * 32);
      bf16x8 k1 = *reinterpret_cast<const bf16x8*>(kb1 + cc * 32);
      bf16x8 k2 = *reinterpret_cast<const bf16x8*>(kb0 + cc * 32 + 32);
      bf16x8 k3 = *reinterpret_cast<const bf16x8*>(kb1 + cc * 32 + 32);
      s0a = __builtin_amdgcn_mfma_f32_16x16x32_bf16(qf[cc], k0, s0a, 0, 0, 0);
      s1a = __builtin_amdgcn_mfma_f32_16x16x32_bf16(qf[cc], k1, s1a, 0, 0, 0);
      s0b = __builtin_amdgcn_mfma_f32_16x16x32_bf16(qf[cc + 1], k2, s0b, 0, 0, 0);
      s1b = __builtin_amdgcn_mfma_f32_16x16x32_bf16(qf[cc + 1], k3, s1b, 0, 0, 0);
    }
    // ---- online softmax, score = -energy; rows r -> n = n0 + g*4 + r ----
    float sc[4];
#pragma unroll
    for (int r = 0; r < 4; r++) {
      float a0 = -(s0a[r] + s0b[r]);
      float a1 = -(s1a[r] + s1b[r]);
      float t = fmaxf(a0, a1);
      t = fmaxf(t, __shfl_xor(t, 1));
      t = fmaxf(t, __shfl_xor(t, 2));
      t = fmaxf(t, __shfl_xor(t, 4));
      t = fmaxf(t, __shfl_xor(t, 8));
      float nm = fmaxf(M[r], t);
      sc[r] = __expf(M[r] - nm);
      M[r] = nm;
      float p0 = __expf(a0 - nm);
      float p1 = __expf(a1 - nm);
      Plds[w][g * 4 + r][l15] = f2b(p0);
      Plds[w][g * 4 + r][16 + l15] = f2b(p1);
      float ps = p0 + p1;
      ps += __shfl_xor(ps, 1);
      ps += __shfl_xor(ps, 2);
      ps += __shfl_xor(ps, 4);
      ps += __shfl_xor(ps, 8);
      L[r] = L[r] * sc[r] + ps;
    }
    // rescale O by per-row factor
#pragma unroll
    for (int i = 0; i < 16; i++) {
#pragma unroll
      for (int r = 0; r < 4; r++) O[i][r] *= sc[r];
    }
    __syncthreads();
    // ---- PV: O[n][c] += P[n][m] * V[m][c];  V[m][c] = x2p[c][m] ----
    bf16x8 pf = *reinterpret_cast<const bf16x8*>(&Plds[w][l15][g * 8]);
    const ushort* vb = cmb + m0;
#pragma unroll
    for (int cs = 0; cs < 16; cs++) {
      bf16x8 vf = *reinterpret_cast<const bf16x8*>(vb + (size_t)(cs * 16 + l15) * NSP);
      O[cs] = __builtin_amdgcn_mfma_f32_16x16x32_bf16(pf, vf, O[cs], 0, 0, 0);
    }
    __syncthreads();
  }
  // ---- epilogue: out = gamma*O/L + x1 ----
  float rl[4];
#pragma unroll
  for (int r = 0; r < 4; r++) rl[r] = gm / L[r];
  size_t ob = (size_t)b * C1 * NSP + n0 + (size_t)g * 4;
#pragma unroll
  for (int cs = 0; cs < 16; cs++) {
#pragma unroll
    for (int r = 0; r < 4; r++) {
      size_t idx = ob + (size_t)(cs * 16 + l15) * NSP + r;
      out[idx] = O[cs][r] * rl[r] + x1[idx];
    }
  }
}

extern "C" void kernel_launch(void* const* d_in, const int* in_sizes, int n_in,
                              void* d_out, int out_size, void* d_ws, size_t ws_size,
                              hipStream_t stream) {
  const float* x1 = (const float*)d_in[0];
  const float* x2 = (const float*)d_in[1];
  const float* W = (const float*)d_in[2];
  const float* bp = (const float*)d_in[3];
  const float* gamma = (const float*)d_in[4];
  float* out = (float*)d_out;

  char* ws = (char*)d_ws;
  float* Wt = (float*)(ws + 0);                 // 512*256*4      =   524288
  ushort* x1t = (ushort*)(ws + 524288);         // 8*3136*256*2   = 12845056
  ushort* cm = (ushort*)(ws + 13369344);        // 8*256*3136*2   = 12845056
  ushort* mc = (ushort*)(ws + 26214400);        // 8*3136*256*2   = 12845056
                                                // total 39,059,456 bytes

  k_wt<<<dim3(512), dim3(256), 0, stream>>>(W, Wt);
  k_x1t<<<dim3(98, 8, 8), dim3(256), 0, stream>>>(x1, x1t);
  k_proj<<<dim3(392), dim3(256), 0, stream>>>(Wt, x2, bp, cm, mc);
  k_attn<<<dim3(784), dim3(128), 0, stream>>>(x1t, cm, mc, x1, gamma, out);
}

// Round 2
// 421.598 us; speedup vs baseline: 2.1087x; 2.1087x over previous
//
#include <hip/hip_runtime.h>
#include <hip/hip_bf16.h>

#define C1 256
#define C2 512
#define NSP 3136   // 56*56
#define NT 98      // KV tiles of 32
#define QT 49      // Q tiles of 64

typedef __attribute__((ext_vector_type(8))) short bf16x8;
typedef __attribute__((ext_vector_type(4))) float f32x4;

__device__ __forceinline__ ushort f2b(float f) {
  __hip_bfloat16 h = __float2bfloat16(f);
  return *reinterpret_cast<ushort*>(&h);
}

__device__ __forceinline__ void gload16(const ushort* g, ushort* l) {
  __builtin_amdgcn_global_load_lds(
      (const __attribute__((address_space(1))) void*)g,
      (__attribute__((address_space(3))) void*)l, 16, 0, 0);
}

// ---------------- K0: Wt[c][o] = W[o][c] ----------------
__global__ void k_wt(const float* __restrict__ W, float* __restrict__ Wt) {
  int c = blockIdx.x;
  int o = threadIdx.x;
  Wt[(size_t)c * C1 + o] = W[(size_t)o * C2 + c];
}

// ---------------- K1: x1t[b][n][c] = bf16(x1[b][c][n]) ----------------
__global__ __launch_bounds__(256) void k_x1t(const float* __restrict__ x1,
                                             ushort* __restrict__ x1t) {
  __shared__ float t[32][33];
  int b = blockIdx.z;
  int n0 = blockIdx.x * 32;
  int c0 = blockIdx.y * 32;
  int tid = threadIdx.x;
  int r = tid >> 3, q = (tid & 7) * 4;
  const float* src = x1 + ((size_t)b * C1 + (c0 + r)) * NSP + n0 + q;
  float4 v = *reinterpret_cast<const float4*>(src);
  t[r][q] = v.x; t[r][q + 1] = v.y; t[r][q + 2] = v.z; t[r][q + 3] = v.w;
  __syncthreads();
  ushort4 o;
  o.x = f2b(t[q + 0][r]); o.y = f2b(t[q + 1][r]);
  o.z = f2b(t[q + 2][r]); o.w = f2b(t[q + 3][r]);
  *reinterpret_cast<ushort4*>(x1t + ((size_t)b * NSP + n0 + r) * C1 + c0 + q) = o;
}

// ---------------- K2: projection, writes frag-ordered Kf and Vf --------
// Kf[b][mt16(196)][cc(8)][lane(64)][8]: lane=(g<<4)|(m&15) holds c=32cc+8g+i, m=16*mt16+(m&15)
// Vf[b][mt32(98)][cs(16)][lane(64)][8]: lane=(g<<4)|l15 holds m=32*mt32+8g+i, c=16cs+l15
__global__ __launch_bounds__(256) void k_proj(const float* __restrict__ Wt,
    const float* __restrict__ x2, const float* __restrict__ bias,
    ushort* __restrict__ Kf, ushort* __restrict__ Vf) {
  int bid = blockIdx.x;          // 8*49
  int b = bid & 7;
  int nc = bid >> 3;
  int tid = threadIdx.x;
  int n = nc * 64 + (tid & 63);
  int o0 = __builtin_amdgcn_readfirstlane((tid >> 6) << 6);
  float acc[64];
#pragma unroll
  for (int i = 0; i < 64; i++) acc[i] = 0.f;
  const float* xp = x2 + (size_t)b * C2 * NSP + n;
  const float* wp = Wt + o0;
  for (int c = 0; c < C2; c++) {
    float v = xp[(size_t)c * NSP];
    const float* wr = wp + c * C1;
#pragma unroll
    for (int i = 0; i < 64; i++) acc[i] = fmaf(wr[i], v, acc[i]);
  }
#pragma unroll
  for (int i = 0; i < 64; i++) acc[i] += bias[o0 + i];

  // ---- Kf writes: 8 x 16B per thread ----
  int mt16 = n >> 4, lm = n & 15;
#pragma unroll
  for (int cc2 = 0; cc2 < 2; cc2++) {
    int cc = (o0 >> 5) + cc2;
#pragma unroll
    for (int g = 0; g < 4; g++) {
      bf16x8 v;
#pragma unroll
      for (int i = 0; i < 8; i++) v[i] = (short)f2b(acc[cc2 * 32 + g * 8 + i]);
      size_t idx = ((((size_t)b * 196 + mt16) * 8 + cc) * 64 + (g * 16 + lm)) * 8;
      *reinterpret_cast<bf16x8*>(Kf + idx) = v;
    }
  }
  // ---- Vf writes: 64 x 2B scatter (8-thread groups merge to 16B) ----
  int mt = n >> 5, gv = (n >> 3) & 3, iv = n & 7;
  size_t vb = (((size_t)b * 98 + mt) * 16) * 512;
#pragma unroll
  for (int j = 0; j < 64; j++) {
    int c = o0 + j;
    Vf[vb + ((size_t)(c >> 4) * 64 + (gv * 16 + (c & 15))) * 8 + iv] = f2b(acc[j]);
  }
}

// ---------------- K3: flash attention, LDS double-buffered K/V --------
__global__ __launch_bounds__(256, 2) void k_attn(
    const ushort* __restrict__ x1t, const ushort* __restrict__ Kf,
    const ushort* __restrict__ Vf, const float* __restrict__ x1,
    const float* __restrict__ gamma, float* __restrict__ out) {
  __shared__ __align__(16) ushort Kt[2][8192];   // 32KB: [mt16 half][cc][lane][8]
  __shared__ __align__(16) ushort Vt[2][8192];   // 32KB: [cs][lane][8]
  __shared__ __align__(16) ushort Plds[4][16][40];
  int bid = blockIdx.x;   // 8*49
  int b = bid & 7;        // batch <-> XCD
  int qt = bid >> 3;
  int tid = threadIdx.x;
  int w = tid >> 6;
  int lane = tid & 63;
  int l15 = lane & 15;
  int g = lane >> 4;
  int n0 = qt * 64 + w * 16;
  float gm = gamma[0];

  // Q fragments (A-operand): row=l15, k = cc*32 + g*8 + i
  bf16x8 qf[8];
  const ushort* qb = x1t + ((size_t)b * NSP + n0 + l15) * C1 + g * 8;
#pragma unroll
  for (int cc = 0; cc < 8; cc++)
    qf[cc] = *reinterpret_cast<const bf16x8*>(qb + cc * 32);

  f32x4 zero = {0.f, 0.f, 0.f, 0.f};
  f32x4 O[16];
#pragma unroll
  for (int i = 0; i < 16; i++) O[i] = zero;
  float M[4], L[4];
#pragma unroll
  for (int r = 0; r < 4; r++) { M[r] = -3.0e38f; L[r] = 0.f; }

  const ushort* kg = Kf + (size_t)b * 196 * 8 * 512;
  const ushort* vg = Vf + (size_t)b * 98 * 16 * 512;
  int soff = w * 2048;   // per-wave staging chunk (4 x 512 elems)

  auto stage = [&](int buf, int t) {
    const ushort* ks = kg + (size_t)t * 8192 + soff + lane * 8;
    const ushort* vs = vg + (size_t)t * 8192 + soff + lane * 8;
    ushort* kl = &Kt[buf][soff];
    ushort* vl = &Vt[buf][soff];
#pragma unroll
    for (int j = 0; j < 4; ++j) {
      gload16(ks + j * 512, kl + j * 512);
      gload16(vs + j * 512, vl + j * 512);
    }
  };

  stage(0, 0);
  __syncthreads();   // drains vmcnt -> tile 0 ready

  for (int t = 0; t < NT; ++t) {
    int cur = t & 1;
    if (t + 1 < NT) stage(cur ^ 1, t + 1);   // issue next tile early

    // ---- S = Q.K^T : 16n x 32m, frag reads conflict-free ----
    f32x4 s0a = zero, s0b = zero, s1a = zero, s1b = zero;
    const ushort* kb = &Kt[cur][0];
#pragma unroll
    for (int cc = 0; cc < 8; cc += 2) {
      bf16x8 k00 = *reinterpret_cast<const bf16x8*>(kb + ((size_t)cc * 64 + lane) * 8);
      bf16x8 k10 = *reinterpret_cast<const bf16x8*>(kb + ((size_t)(8 + cc) * 64 + lane) * 8);
      bf16x8 k01 = *reinterpret_cast<const bf16x8*>(kb + ((size_t)(cc + 1) * 64 + lane) * 8);
      bf16x8 k11 = *reinterpret_cast<const bf16x8*>(kb + ((size_t)(9 + cc) * 64 + lane) * 8);
      s0a = __builtin_amdgcn_mfma_f32_16x16x32_bf16(qf[cc], k00, s0a, 0, 0, 0);
      s1a = __builtin_amdgcn_mfma_f32_16x16x32_bf16(qf[cc], k10, s1a, 0, 0, 0);
      s0b = __builtin_amdgcn_mfma_f32_16x16x32_bf16(qf[cc + 1], k01, s0b, 0, 0, 0);
      s1b = __builtin_amdgcn_mfma_f32_16x16x32_bf16(qf[cc + 1], k11, s1b, 0, 0, 0);
    }
    // ---- online softmax, score = -energy ----
    float sc[4];
#pragma unroll
    for (int r = 0; r < 4; r++) {
      float a0 = -(s0a[r] + s0b[r]);
      float a1 = -(s1a[r] + s1b[r]);
      float mx = fmaxf(a0, a1);
      mx = fmaxf(mx, __shfl_xor(mx, 1));
      mx = fmaxf(mx, __shfl_xor(mx, 2));
      mx = fmaxf(mx, __shfl_xor(mx, 4));
      mx = fmaxf(mx, __shfl_xor(mx, 8));
      float nm = fmaxf(M[r], mx);
      sc[r] = __expf(M[r] - nm);
      M[r] = nm;
      float p0 = __expf(a0 - nm);
      float p1 = __expf(a1 - nm);
      Plds[w][g * 4 + r][l15] = f2b(p0);
      Plds[w][g * 4 + r][16 + l15] = f2b(p1);
      float ps = p0 + p1;
      ps += __shfl_xor(ps, 1);
      ps += __shfl_xor(ps, 2);
      ps += __shfl_xor(ps, 4);
      ps += __shfl_xor(ps, 8);
      L[r] = L[r] * sc[r] + ps;
    }
#pragma unroll
    for (int i = 0; i < 16; i++) {
#pragma unroll
      for (int r = 0; r < 4; r++) O[i][r] *= sc[r];
    }
    // wave-local P handoff (no block barrier needed: Plds is per-wave)
    asm volatile("s_waitcnt lgkmcnt(0)" ::: "memory");
    bf16x8 pf = *reinterpret_cast<const bf16x8*>(&Plds[w][l15][g * 8]);
    // ---- PV: O[n][c] += P[n][m] V[m][c], frag reads conflict-free ----
    const ushort* vb2 = &Vt[cur][0];
#pragma unroll
    for (int cs = 0; cs < 16; ++cs) {
      bf16x8 vf = *reinterpret_cast<const bf16x8*>(vb2 + ((size_t)cs * 64 + lane) * 8);
      O[cs] = __builtin_amdgcn_mfma_f32_16x16x32_bf16(pf, vf, O[cs], 0, 0, 0);
    }
    __syncthreads();  // drains vmcnt (next tile staged) + all waves done with cur
  }

  // ---- epilogue: out = gamma*O/L + x1 ----
  float rl[4];
#pragma unroll
  for (int r = 0; r < 4; r++) rl[r] = gm / L[r];
  size_t ob = (size_t)b * C1 * NSP + n0 + (size_t)g * 4;
#pragma unroll
  for (int cs = 0; cs < 16; cs++) {
#pragma unroll
    for (int r = 0; r < 4; r++) {
      size_t idx = ob + (size_t)(cs * 16 + l15) * NSP + r;
      out[idx] = O[cs][r] * rl[r] + x1[idx];
    }
  }
}

extern "C" void kernel_launch(void* const* d_in, const int* in_sizes, int n_in,
                              void* d_out, int out_size, void* d_ws, size_t ws_size,
                              hipStream_t stream) {
  const float* x1 = (const float*)d_in[0];
  const float* x2 = (const float*)d_in[1];
  const float* W = (const float*)d_in[2];
  const float* bp = (const float*)d_in[3];
  const float* gamma = (const float*)d_in[4];
  float* out = (float*)d_out;

  char* ws = (char*)d_ws;
  float* Wt = (float*)(ws + 0);                 // 512*256*4      =   524288
  ushort* x1t = (ushort*)(ws + 524288);         // 8*3136*256*2   = 12845056
  ushort* Kf = (ushort*)(ws + 13369344);        // 8*196*8*64*8*2 = 12845056
  ushort* Vf = (ushort*)(ws + 26214400);        // 8*98*16*64*8*2 = 12845056
                                                // total 39,059,456 bytes

  k_wt<<<dim3(512), dim3(256), 0, stream>>>(W, Wt);
  k_x1t<<<dim3(98, 8, 8), dim3(256), 0, stream>>>(x1, x1t);
  k_proj<<<dim3(392), dim3(256), 0, stream>>>(Wt, x2, bp, Kf, Vf);
  k_attn<<<dim3(392), dim3(256), 0, stream>>>(x1t, Kf, Vf, x1, gamma, out);
}

// Round 3
// 263.382 us; speedup vs baseline: 3.3755x; 1.6007x over previous
//
#include <hip/hip_runtime.h>
#include <hip/hip_bf16.h>

#define C1 256
#define C2 512
#define NSP 3136   // 56*56
#define NT 98      // KV tiles of 32
#define QT 49      // Q tiles of 64

typedef __attribute__((ext_vector_type(8))) short bf16x8;
typedef __attribute__((ext_vector_type(4))) float f32x4;

__device__ __forceinline__ ushort f2b(float f) {
  __hip_bfloat16 h = __float2bfloat16(f);
  return *reinterpret_cast<ushort*>(&h);
}

__device__ __forceinline__ void gload16(const ushort* g, ushort* l) {
  __builtin_amdgcn_global_load_lds(
      (const __attribute__((address_space(1))) void*)g,
      (__attribute__((address_space(3))) void*)l, 16, 0, 0);
}

// ---- K0: Wf[ot16][cc][lane][8] = bf16 A-frag pack of W[o][c] ----------
__global__ __launch_bounds__(256) void k_wtf(const float* __restrict__ W,
                                             ushort* __restrict__ Wf) {
  int ot = blockIdx.x;            // 16
  int tid = threadIdx.x;
  int lane = tid & 63, l15 = lane & 15, g = (lane >> 4) & 3;
  int cc0 = (tid >> 6) * 4;
  const float* src = W + (size_t)(ot * 16 + l15) * C2 + g * 8;
#pragma unroll
  for (int k = 0; k < 4; k++) {
    int cc = cc0 + k;
    float4 u0 = *reinterpret_cast<const float4*>(src + cc * 32);
    float4 u1 = *reinterpret_cast<const float4*>(src + cc * 32 + 4);
    bf16x8 v;
    v[0] = (short)f2b(u0.x); v[1] = (short)f2b(u0.y);
    v[2] = (short)f2b(u0.z); v[3] = (short)f2b(u0.w);
    v[4] = (short)f2b(u1.x); v[5] = (short)f2b(u1.y);
    v[6] = (short)f2b(u1.z); v[7] = (short)f2b(u1.w);
    *reinterpret_cast<bf16x8*>(Wf + ((size_t)(ot * 16 + cc)) * 512 + lane * 8) = v;
  }
}

// ---- K1: x1t[b][n][c] = bf16(x1[b][c][n]) -----------------------------
__global__ __launch_bounds__(256) void k_x1t(const float* __restrict__ x1,
                                             ushort* __restrict__ x1t) {
  __shared__ float t[32][33];
  int b = blockIdx.z;
  int n0 = blockIdx.x * 32;
  int c0 = blockIdx.y * 32;
  int tid = threadIdx.x;
  int r = tid >> 3, q = (tid & 7) * 4;
  const float* src = x1 + ((size_t)b * C1 + (c0 + r)) * NSP + n0 + q;
  float4 v = *reinterpret_cast<const float4*>(src);
  t[r][q] = v.x; t[r][q + 1] = v.y; t[r][q + 2] = v.z; t[r][q + 3] = v.w;
  __syncthreads();
  ushort4 o;
  o.x = f2b(t[q + 0][r]); o.y = f2b(t[q + 1][r]);
  o.z = f2b(t[q + 2][r]); o.w = f2b(t[q + 3][r]);
  *reinterpret_cast<ushort4*>(x1t + ((size_t)b * NSP + n0 + r) * C1 + c0 + q) = o;
}

// ---- K2: x2f[b][nt16][cc][lane][8] = bf16 B-frag pack of x2[b][c][n] --
__global__ __launch_bounds__(256) void k_x2f(const float* __restrict__ x2,
                                             ushort* __restrict__ x2f) {
  __shared__ float t[32][33];
  int b = blockIdx.z;
  int n0 = blockIdx.x * 32;   // 98
  int cc = blockIdx.y;        // 16
  int c0 = cc * 32;
  int tid = threadIdx.x;
  int r = tid >> 3, q = (tid & 7) * 4;
  const float* src = x2 + ((size_t)b * C2 + (c0 + r)) * NSP + n0 + q;
  float4 v = *reinterpret_cast<const float4*>(src);
  t[r][q] = v.x; t[r][q + 1] = v.y; t[r][q + 2] = v.z; t[r][q + 3] = v.w;
  __syncthreads();
  int l15 = tid & 15, g = (tid >> 4) & 3, sub = tid >> 6;
  int ntl = sub & 1, ih = sub >> 1;
  int nl = ntl * 16 + l15;
  int cl = g * 8 + ih * 4;
  ushort4 o;
  o.x = f2b(t[cl + 0][nl]); o.y = f2b(t[cl + 1][nl]);
  o.z = f2b(t[cl + 2][nl]); o.w = f2b(t[cl + 3][nl]);
  int nt16 = (n0 >> 4) + ntl;
  *reinterpret_cast<ushort4*>(
      x2f + (((size_t)b * 196 + nt16) * 16 + cc) * 512 + (size_t)(tid & 63) * 8 + ih * 4) = o;
}

// ---- K3: MFMA projection GEMM: x2p[o][n] = W@x2 + b --------------------
// block = 128o x 64n, 4 waves of 64o x 32n; K=512 in 16 steps of 32.
// Epilogue writes Kf/Vf in k_attn fragment layouts.
__global__ __launch_bounds__(256) void k_proj(const ushort* __restrict__ Wf,
    const ushort* __restrict__ x2f, const float* __restrict__ bias,
    ushort* __restrict__ Kf, ushort* __restrict__ Vf) {
  __shared__ __align__(16) ushort WL[2][8][512];   // 16 KB
  __shared__ __align__(16) ushort XL[2][4][512];   // 8 KB
  int bid = blockIdx.x;      // 784 = 8b * 49nt * 2oh
  int b = bid & 7;           // batch <-> XCD
  int tq = bid >> 3;         // 0..97
  int oh = tq & 1;
  int nt = tq >> 1;          // 0..48
  int tid = threadIdx.x;
  int w = tid >> 6, lane = tid & 63, l15 = lane & 15, g = lane >> 4;
  int wq = w >> 1, wn = w & 1;
  int ot0 = oh * 8;
  int nt0 = nt * 4;

  auto stage = [&](int buf, int cc) {
#pragma unroll
    for (int j = 0; j < 3; j++) {
      int chunk = w * 3 + j;
      if (chunk < 8) {
        gload16(Wf + ((size_t)(ot0 + chunk) * 16 + cc) * 512 + lane * 8,
                &WL[buf][chunk][0]);
      } else {
        gload16(x2f + (((size_t)b * 196 + nt0 + (chunk - 8)) * 16 + cc) * 512 + lane * 8,
                &XL[buf][chunk - 8][0]);
      }
    }
  };

  f32x4 zero = {0.f, 0.f, 0.f, 0.f};
  f32x4 acc[4][2];
#pragma unroll
  for (int a = 0; a < 4; a++)
#pragma unroll
    for (int v = 0; v < 2; v++) acc[a][v] = zero;

  stage(0, 0);
  __syncthreads();

  for (int cc = 0; cc < 16; ++cc) {
    int cur = cc & 1;
    if (cc < 15) stage(cur ^ 1, cc + 1);
    bf16x8 A[4], Bf[2];
#pragma unroll
    for (int a = 0; a < 4; a++)
      A[a] = *reinterpret_cast<const bf16x8*>(&WL[cur][wq * 4 + a][lane * 8]);
#pragma unroll
    for (int v = 0; v < 2; v++)
      Bf[v] = *reinterpret_cast<const bf16x8*>(&XL[cur][wn * 2 + v][lane * 8]);
#pragma unroll
    for (int a = 0; a < 4; a++)
#pragma unroll
      for (int v = 0; v < 2; v++)
        acc[a][v] = __builtin_amdgcn_mfma_f32_16x16x32_bf16(A[a], Bf[v], acc[a][v], 0, 0, 0);
    __syncthreads();
  }

  // ---- epilogue: + bias, write Kf & Vf fragment layouts ----
  int obase = oh * 128 + wq * 64;
  float4 bias4[4];
#pragma unroll
  for (int a = 0; a < 4; a++)
    bias4[a] = *reinterpret_cast<const float4*>(&bias[obase + a * 16 + g * 4]);

  // Kf[b][n>>4][o>>5][(((o>>3)&3)<<4)|(n&15)][o&7]
  int gk = (g & 1) * 4;
#pragma unroll
  for (int a = 0; a < 4; a++) {
    int laneK = (((2 * a + (g >> 1)) & 3) << 4) | l15;
    size_t oK = (size_t)(oh * 4 + wq * 2 + (a >> 1));
#pragma unroll
    for (int v = 0; v < 2; v++) {
      int nK = nt * 4 + wn * 2 + v;
      ushort4 st;
      st.x = f2b(acc[a][v][0] + bias4[a].x);
      st.y = f2b(acc[a][v][1] + bias4[a].y);
      st.z = f2b(acc[a][v][2] + bias4[a].z);
      st.w = f2b(acc[a][v][3] + bias4[a].w);
      *reinterpret_cast<ushort4*>(
          Kf + ((((size_t)b * 196 + nK) * 8 + oK) * 64 + laneK) * 8 + gk) = st;
    }
  }
  // Vf[b][n>>5][o>>4][(((n>>3)&3)<<4)|(o&15)][n&7]
  int nV = nt * 2 + wn;
#pragma unroll
  for (int v = 0; v < 2; v++) {
    int gv = ((v * 2 + (l15 >> 3)) & 3) << 4;
    int iV = l15 & 7;
#pragma unroll
    for (int a = 0; a < 4; a++) {
      int cs = oh * 8 + wq * 4 + a;
      size_t basev = ((((size_t)b * 98 + nV) * 16 + cs) * 64 + gv) * 8 + iV;
      const float* bp4 = reinterpret_cast<const float*>(&bias4[a]);
#pragma unroll
      for (int r = 0; r < 4; r++)
        Vf[basev + (size_t)(g * 4 + r) * 8] = f2b(acc[a][v][r] + bp4[r]);
    }
  }
}

// ---- K4: flash attention, LDS double-buffered K/V ---------------------
__global__ __launch_bounds__(256, 2) void k_attn(
    const ushort* __restrict__ x1t, const ushort* __restrict__ Kf,
    const ushort* __restrict__ Vf, const float* __restrict__ x1,
    const float* __restrict__ gamma, float* __restrict__ out) {
  __shared__ __align__(16) ushort Kt[2][8192];
  __shared__ __align__(16) ushort Vt[2][8192];
  __shared__ __align__(16) ushort Plds[4][16][40];
  int bid = blockIdx.x;   // 8*49
  int b = bid & 7;        // batch <-> XCD
  int qt = bid >> 3;
  int tid = threadIdx.x;
  int w = tid >> 6;
  int lane = tid & 63;
  int l15 = lane & 15;
  int g = lane >> 4;
  int n0 = qt * 64 + w * 16;
  float gm = gamma[0];

  bf16x8 qf[8];
  const ushort* qb = x1t + ((size_t)b * NSP + n0 + l15) * C1 + g * 8;
#pragma unroll
  for (int cc = 0; cc < 8; cc++)
    qf[cc] = *reinterpret_cast<const bf16x8*>(qb + cc * 32);

  f32x4 zero = {0.f, 0.f, 0.f, 0.f};
  f32x4 O[16];
#pragma unroll
  for (int i = 0; i < 16; i++) O[i] = zero;
  float M[4], L[4];
#pragma unroll
  for (int r = 0; r < 4; r++) { M[r] = -3.0e38f; L[r] = 0.f; }

  const ushort* kg = Kf + (size_t)b * 196 * 8 * 512;
  const ushort* vg = Vf + (size_t)b * 98 * 16 * 512;
  int soff = w * 2048;

  auto stage = [&](int buf, int t) {
    const ushort* ks = kg + (size_t)t * 8192 + soff + lane * 8;
    const ushort* vs = vg + (size_t)t * 8192 + soff + lane * 8;
    ushort* kl = &Kt[buf][soff];
    ushort* vl = &Vt[buf][soff];
#pragma unroll
    for (int j = 0; j < 4; ++j) {
      gload16(ks + j * 512, kl + j * 512);
      gload16(vs + j * 512, vl + j * 512);
    }
  };

  stage(0, 0);
  __syncthreads();

  for (int t = 0; t < NT; ++t) {
    int cur = t & 1;
    if (t + 1 < NT) stage(cur ^ 1, t + 1);

    f32x4 s0a = zero, s0b = zero, s1a = zero, s1b = zero;
    const ushort* kb = &Kt[cur][0];
#pragma unroll
    for (int cc = 0; cc < 8; cc += 2) {
      bf16x8 k00 = *reinterpret_cast<const bf16x8*>(kb + ((size_t)cc * 64 + lane) * 8);
      bf16x8 k10 = *reinterpret_cast<const bf16x8*>(kb + ((size_t)(8 + cc) * 64 + lane) * 8);
      bf16x8 k01 = *reinterpret_cast<const bf16x8*>(kb + ((size_t)(cc + 1) * 64 + lane) * 8);
      bf16x8 k11 = *reinterpret_cast<const bf16x8*>(kb + ((size_t)(9 + cc) * 64 + lane) * 8);
      s0a = __builtin_amdgcn_mfma_f32_16x16x32_bf16(qf[cc], k00, s0a, 0, 0, 0);
      s1a = __builtin_amdgcn_mfma_f32_16x16x32_bf16(qf[cc], k10, s1a, 0, 0, 0);
      s0b = __builtin_amdgcn_mfma_f32_16x16x32_bf16(qf[cc + 1], k01, s0b, 0, 0, 0);
      s1b = __builtin_amdgcn_mfma_f32_16x16x32_bf16(qf[cc + 1], k11, s1b, 0, 0, 0);
    }
    float sc[4];
#pragma unroll
    for (int r = 0; r < 4; r++) {
      float a0 = -(s0a[r] + s0b[r]);
      float a1 = -(s1a[r] + s1b[r]);
      float mx = fmaxf(a0, a1);
      mx = fmaxf(mx, __shfl_xor(mx, 1));
      mx = fmaxf(mx, __shfl_xor(mx, 2));
      mx = fmaxf(mx, __shfl_xor(mx, 4));
      mx = fmaxf(mx, __shfl_xor(mx, 8));
      float nm = fmaxf(M[r], mx);
      sc[r] = __expf(M[r] - nm);
      M[r] = nm;
      float p0 = __expf(a0 - nm);
      float p1 = __expf(a1 - nm);
      Plds[w][g * 4 + r][l15] = f2b(p0);
      Plds[w][g * 4 + r][16 + l15] = f2b(p1);
      float ps = p0 + p1;
      ps += __shfl_xor(ps, 1);
      ps += __shfl_xor(ps, 2);
      ps += __shfl_xor(ps, 4);
      ps += __shfl_xor(ps, 8);
      L[r] = L[r] * sc[r] + ps;
    }
#pragma unroll
    for (int i = 0; i < 16; i++) {
#pragma unroll
      for (int r = 0; r < 4; r++) O[i][r] *= sc[r];
    }
    asm volatile("s_waitcnt lgkmcnt(0)" ::: "memory");
    bf16x8 pf = *reinterpret_cast<const bf16x8*>(&Plds[w][l15][g * 8]);
    const ushort* vb2 = &Vt[cur][0];
#pragma unroll
    for (int cs = 0; cs < 16; ++cs) {
      bf16x8 vf = *reinterpret_cast<const bf16x8*>(vb2 + ((size_t)cs * 64 + lane) * 8);
      O[cs] = __builtin_amdgcn_mfma_f32_16x16x32_bf16(pf, vf, O[cs], 0, 0, 0);
    }
    __syncthreads();
  }

  float rl[4];
#pragma unroll
  for (int r = 0; r < 4; r++) rl[r] = gm / L[r];
  size_t ob = (size_t)b * C1 * NSP + n0 + (size_t)g * 4;
#pragma unroll
  for (int cs = 0; cs < 16; cs++) {
#pragma unroll
    for (int r = 0; r < 4; r++) {
      size_t idx = ob + (size_t)(cs * 16 + l15) * NSP + r;
      out[idx] = O[cs][r] * rl[r] + x1[idx];
    }
  }
}

extern "C" void kernel_launch(void* const* d_in, const int* in_sizes, int n_in,
                              void* d_out, int out_size, void* d_ws, size_t ws_size,
                              hipStream_t stream) {
  const float* x1 = (const float*)d_in[0];
  const float* x2 = (const float*)d_in[1];
  const float* W = (const float*)d_in[2];
  const float* bp = (const float*)d_in[3];
  const float* gamma = (const float*)d_in[4];
  float* out = (float*)d_out;

  char* ws = (char*)d_ws;
  ushort* Wf = (ushort*)(ws + 0);               // 16*16*512*2    =   262144
  ushort* x1t = (ushort*)(ws + 524288);         // 8*3136*256*2   = 12845056
  ushort* Kf = (ushort*)(ws + 13369344);        // 8*196*8*64*8*2 = 12845056
  ushort* Vf = (ushort*)(ws + 26214400);        // 8*98*16*64*8*2 = 12845056
  // x2f lives in d_out (25,690,112 B, exact fit): dead until k_attn epilogue.
  ushort* x2f = (ushort*)d_out;                 // 8*196*16*512*2 = 25690112

  k_wtf<<<dim3(16), dim3(256), 0, stream>>>(W, Wf);
  k_x1t<<<dim3(98, 8, 8), dim3(256), 0, stream>>>(x1, x1t);
  k_x2f<<<dim3(98, 16, 8), dim3(256), 0, stream>>>(x2, x2f);
  k_proj<<<dim3(784), dim3(256), 0, stream>>>(Wf, x2f, bp, Kf, Vf);
  k_attn<<<dim3(392), dim3(256), 0, stream>>>(x1t, Kf, Vf, x1, gamma, out);
}

// Round 5
// 255.636 us; speedup vs baseline: 3.4777x; 1.0303x over previous
//
#include <hip/hip_runtime.h>
#include <hip/hip_bf16.h>

#define C1 256
#define C2 512
#define NSP 3136   // 56*56
#define NT 98      // KV tiles of 32

typedef __attribute__((ext_vector_type(8))) short bf16x8;
typedef __attribute__((ext_vector_type(4))) float f32x4;

__device__ __forceinline__ ushort f2b(float f) {
  __hip_bfloat16 h = __float2bfloat16(f);
  return *reinterpret_cast<ushort*>(&h);
}
__device__ __forceinline__ float b2f(ushort u) {
  union { unsigned int i; float f; } v; v.i = ((unsigned int)u) << 16; return v.f;
}
__device__ __forceinline__ void gload16(const ushort* g, ushort* l) {
  __builtin_amdgcn_global_load_lds(
      (const __attribute__((address_space(1))) void*)g,
      (__attribute__((address_space(3))) void*)l, 16, 0, 0);
}
__device__ __forceinline__ void block_bar() {
  asm volatile("" ::: "memory");
  __builtin_amdgcn_s_barrier();
  asm volatile("" ::: "memory");
}

// ---- K0: Wf[ot16][cc][lane][8] = bf16 A-frag pack of W[o][c] ----------
__global__ __launch_bounds__(256) void k_wtf(const float* __restrict__ W,
                                             ushort* __restrict__ Wf) {
  int ot = blockIdx.x;            // 16
  int tid = threadIdx.x;
  int lane = tid & 63, l15 = lane & 15, g = (lane >> 4) & 3;
  int cc0 = (tid >> 6) * 4;
  const float* src = W + (size_t)(ot * 16 + l15) * C2 + g * 8;
#pragma unroll
  for (int k = 0; k < 4; k++) {
    int cc = cc0 + k;
    float4 u0 = *reinterpret_cast<const float4*>(src + cc * 32);
    float4 u1 = *reinterpret_cast<const float4*>(src + cc * 32 + 4);
    bf16x8 v;
    v[0] = (short)f2b(u0.x); v[1] = (short)f2b(u0.y);
    v[2] = (short)f2b(u0.z); v[3] = (short)f2b(u0.w);
    v[4] = (short)f2b(u1.x); v[5] = (short)f2b(u1.y);
    v[6] = (short)f2b(u1.z); v[7] = (short)f2b(u1.w);
    *reinterpret_cast<bf16x8*>(Wf + ((size_t)(ot * 16 + cc)) * 512 + lane * 8) = v;
  }
}

// ---- K1: x1t[b][n][c] = bf16(x1[b][c][n]) -----------------------------
__global__ __launch_bounds__(256) void k_x1t(const float* __restrict__ x1,
                                             ushort* __restrict__ x1t) {
  __shared__ float t[32][33];
  int b = blockIdx.z;
  int n0 = blockIdx.x * 32;
  int c0 = blockIdx.y * 32;
  int tid = threadIdx.x;
  int r = tid >> 3, q = (tid & 7) * 4;
  const float* src = x1 + ((size_t)b * C1 + (c0 + r)) * NSP + n0 + q;
  float4 v = *reinterpret_cast<const float4*>(src);
  t[r][q] = v.x; t[r][q + 1] = v.y; t[r][q + 2] = v.z; t[r][q + 3] = v.w;
  __syncthreads();
  ushort4 o;
  o.x = f2b(t[q + 0][r]); o.y = f2b(t[q + 1][r]);
  o.z = f2b(t[q + 2][r]); o.w = f2b(t[q + 3][r]);
  *reinterpret_cast<ushort4*>(x1t + ((size_t)b * NSP + n0 + r) * C1 + c0 + q) = o;
}

// ---- K2: x2f[b][nt16][cc][lane][8] = bf16 B-frag pack of x2[b][c][n] --
__global__ __launch_bounds__(256) void k_x2f(const float* __restrict__ x2,
                                             ushort* __restrict__ x2f) {
  __shared__ float t[32][33];
  int b = blockIdx.z;
  int n0 = blockIdx.x * 32;   // 98
  int cc = blockIdx.y;        // 16
  int c0 = cc * 32;
  int tid = threadIdx.x;
  int r = tid >> 3, q = (tid & 7) * 4;
  const float* src = x2 + ((size_t)b * C2 + (c0 + r)) * NSP + n0 + q;
  float4 v = *reinterpret_cast<const float4*>(src);
  t[r][q] = v.x; t[r][q + 1] = v.y; t[r][q + 2] = v.z; t[r][q + 3] = v.w;
  __syncthreads();
  int l15 = tid & 15, g = (tid >> 4) & 3, sub = tid >> 6;
  int ntl = sub & 1, ih = sub >> 1;
  int nl = ntl * 16 + l15;
  int cl = g * 8 + ih * 4;
  ushort4 o;
  o.x = f2b(t[cl + 0][nl]); o.y = f2b(t[cl + 1][nl]);
  o.z = f2b(t[cl + 2][nl]); o.w = f2b(t[cl + 3][nl]);
  int nt16 = (n0 >> 4) + ntl;
  *reinterpret_cast<ushort4*>(
      x2f + (((size_t)b * 196 + nt16) * 16 + cc) * 512 + (size_t)(tid & 63) * 8 + ih * 4) = o;
}

// ---- K3: MFMA projection GEMM, epilogue writes Kf/Vf frag layouts ------
__global__ __launch_bounds__(256) void k_proj(const ushort* __restrict__ Wf,
    const ushort* __restrict__ x2f, const float* __restrict__ bias,
    ushort* __restrict__ Kf, ushort* __restrict__ Vf) {
  __shared__ __align__(16) ushort WL[2][8][512];
  __shared__ __align__(16) ushort XL[2][4][512];
  int bid = blockIdx.x;      // 784 = 8b * 49nt * 2oh
  int b = bid & 7;
  int tq = bid >> 3;
  int oh = tq & 1;
  int nt = tq >> 1;
  int tid = threadIdx.x;
  int w = tid >> 6, lane = tid & 63, l15 = lane & 15, g = lane >> 4;
  int wq = w >> 1, wn = w & 1;
  int ot0 = oh * 8;
  int nt0 = nt * 4;

  auto stage = [&](int buf, int cc) {
#pragma unroll
    for (int j = 0; j < 3; j++) {
      int chunk = w * 3 + j;
      if (chunk < 8) {
        gload16(Wf + ((size_t)(ot0 + chunk) * 16 + cc) * 512 + lane * 8,
                &WL[buf][chunk][0]);
      } else {
        gload16(x2f + (((size_t)b * 196 + nt0 + (chunk - 8)) * 16 + cc) * 512 + lane * 8,
                &XL[buf][chunk - 8][0]);
      }
    }
  };

  f32x4 zero = {0.f, 0.f, 0.f, 0.f};
  f32x4 acc[4][2];
#pragma unroll
  for (int a = 0; a < 4; a++)
#pragma unroll
    for (int v = 0; v < 2; v++) acc[a][v] = zero;

  stage(0, 0);
  __syncthreads();

  for (int cc = 0; cc < 16; ++cc) {
    int cur = cc & 1;
    if (cc < 15) stage(cur ^ 1, cc + 1);
    bf16x8 A[4], Bf[2];
#pragma unroll
    for (int a = 0; a < 4; a++)
      A[a] = *reinterpret_cast<const bf16x8*>(&WL[cur][wq * 4 + a][lane * 8]);
#pragma unroll
    for (int v = 0; v < 2; v++)
      Bf[v] = *reinterpret_cast<const bf16x8*>(&XL[cur][wn * 2 + v][lane * 8]);
#pragma unroll
    for (int a = 0; a < 4; a++)
#pragma unroll
      for (int v = 0; v < 2; v++)
        acc[a][v] = __builtin_amdgcn_mfma_f32_16x16x32_bf16(A[a], Bf[v], acc[a][v], 0, 0, 0);
    __syncthreads();
  }

  int obase = oh * 128 + wq * 64;
  float4 bias4[4];
#pragma unroll
  for (int a = 0; a < 4; a++)
    bias4[a] = *reinterpret_cast<const float4*>(&bias[obase + a * 16 + g * 4]);

  int gk = (g & 1) * 4;
#pragma unroll
  for (int a = 0; a < 4; a++) {
    int laneK = (((2 * a + (g >> 1)) & 3) << 4) | l15;
    size_t oK = (size_t)(oh * 4 + wq * 2 + (a >> 1));
#pragma unroll
    for (int v = 0; v < 2; v++) {
      int nK = nt * 4 + wn * 2 + v;
      ushort4 st;
      st.x = f2b(acc[a][v][0] + bias4[a].x);
      st.y = f2b(acc[a][v][1] + bias4[a].y);
      st.z = f2b(acc[a][v][2] + bias4[a].z);
      st.w = f2b(acc[a][v][3] + bias4[a].w);
      *reinterpret_cast<ushort4*>(
          Kf + ((((size_t)b * 196 + nK) * 8 + oK) * 64 + laneK) * 8 + gk) = st;
    }
  }
  int nV = nt * 2 + wn;
#pragma unroll
  for (int v = 0; v < 2; v++) {
    int gv = ((v * 2 + (l15 >> 3)) & 3) << 4;
    int iV = l15 & 7;
#pragma unroll
    for (int a = 0; a < 4; a++) {
      int cs = oh * 8 + wq * 4 + a;
      size_t basev = ((((size_t)b * 98 + nV) * 16 + cs) * 64 + gv) * 8 + iV;
      const float* bp4 = reinterpret_cast<const float*>(&bias4[a]);
#pragma unroll
      for (int r = 0; r < 4; r++)
        Vf[basev + (size_t)(g * 4 + r) * 8] = f2b(acc[a][v][r] + bp4[r]);
    }
  }
}

// ---- K4: flash attention. SPLIT=1: half KV range, partial out. --------
template<int SPLIT>
__global__ __launch_bounds__(256, 3) void k_attn(
    const ushort* __restrict__ x1t, const ushort* __restrict__ Kf,
    const ushort* __restrict__ Vf, const float* __restrict__ x1,
    const float* __restrict__ gamma, float* __restrict__ out,
    ushort* __restrict__ Po, float* __restrict__ Mv, float* __restrict__ Lv) {
  __shared__ __align__(16) ushort Kt[2][8192];   // 32KB double-buffered K
  __shared__ __align__(16) ushort Vt[8192];      // 16KB single-buffered V
  __shared__ __align__(16) ushort Plds[4][16][36];
  int bid = blockIdx.x;
  int b = bid & 7;                         // batch <-> XCD
  int qt = SPLIT ? (bid >> 4) : (bid >> 3);
  int h = SPLIT ? ((bid >> 3) & 1) : 0;
  int t0 = h * 49;
  int t1 = SPLIT ? (t0 + 49) : NT;
  int tid = threadIdx.x;
  int w = tid >> 6;
  int lane = tid & 63;
  int l15 = lane & 15;
  int g = lane >> 4;
  int n0 = qt * 64 + w * 16;

  // Q fragments (A-operand): row=l15, k = cc*32 + g*8 + i
  bf16x8 qf[8];
  const ushort* qb = x1t + ((size_t)b * NSP + n0 + l15) * C1 + g * 8;
#pragma unroll
  for (int cc = 0; cc < 8; cc++)
    qf[cc] = *reinterpret_cast<const bf16x8*>(qb + cc * 32);

  f32x4 zero = {0.f, 0.f, 0.f, 0.f};
  f32x4 O[16];
#pragma unroll
  for (int i = 0; i < 16; i++) O[i] = zero;
  f32x4 O17 = zero;                 // row-sum accumulator (L) via ones-MFMA
  float M[4];
#pragma unroll
  for (int r = 0; r < 4; r++) M[r] = -3.0e38f;
  bf16x8 onesf;
#pragma unroll
  for (int i = 0; i < 8; i++) onesf[i] = (short)0x3F80;  // bf16 1.0

  const ushort* kg = Kf + (size_t)b * 196 * 8 * 512;
  const ushort* vg = Vf + (size_t)b * 98 * 16 * 512;
  int soff = w * 2048;

  // prologue: stage K[t0] into Kt[0]
  {
    const ushort* ks = kg + (size_t)t0 * 8192 + soff + lane * 8;
#pragma unroll
    for (int j = 0; j < 4; ++j) gload16(ks + j * 512, &Kt[0][soff] + j * 512);
  }
  asm volatile("s_waitcnt vmcnt(0)" ::: "memory");
  block_bar();

  int cur = 0;
  for (int t = t0; t < t1; ++t) {
    // issue V[t] (4 loads, oldest) then K[t+1] (4 loads)
    {
      const ushort* vs = vg + (size_t)t * 8192 + soff + lane * 8;
#pragma unroll
      for (int j = 0; j < 4; ++j) gload16(vs + j * 512, &Vt[soff] + j * 512);
    }
    asm volatile("" ::: "memory");   // keep V-issue before K-issue (vmcnt order)
    if (t + 1 < t1) {
      const ushort* ks = kg + (size_t)(t + 1) * 8192 + soff + lane * 8;
#pragma unroll
      for (int j = 0; j < 4; ++j) gload16(ks + j * 512, &Kt[cur ^ 1][soff] + j * 512);
    }
    asm volatile("" ::: "memory");

    // ---- S = Q.K^T : 16n x 32m from Kt[cur] ----
    f32x4 s0a = zero, s0b = zero, s1a = zero, s1b = zero;
    const ushort* kb = &Kt[cur][0];
    __builtin_amdgcn_s_setprio(1);
#pragma unroll
    for (int cc = 0; cc < 8; cc += 2) {
      bf16x8 k00 = *reinterpret_cast<const bf16x8*>(kb + ((size_t)cc * 64 + lane) * 8);
      bf16x8 k10 = *reinterpret_cast<const bf16x8*>(kb + ((size_t)(8 + cc) * 64 + lane) * 8);
      bf16x8 k01 = *reinterpret_cast<const bf16x8*>(kb + ((size_t)(cc + 1) * 64 + lane) * 8);
      bf16x8 k11 = *reinterpret_cast<const bf16x8*>(kb + ((size_t)(9 + cc) * 64 + lane) * 8);
      s0a = __builtin_amdgcn_mfma_f32_16x16x32_bf16(qf[cc], k00, s0a, 0, 0, 0);
      s1a = __builtin_amdgcn_mfma_f32_16x16x32_bf16(qf[cc], k10, s1a, 0, 0, 0);
      s0b = __builtin_amdgcn_mfma_f32_16x16x32_bf16(qf[cc + 1], k01, s0b, 0, 0, 0);
      s1b = __builtin_amdgcn_mfma_f32_16x16x32_bf16(qf[cc + 1], k11, s1b, 0, 0, 0);
    }
    __builtin_amdgcn_s_setprio(0);

    // ---- online softmax with defer-max (THR=3) ----
    float a0[4], a1[4], tmax[4];
#pragma unroll
    for (int r = 0; r < 4; r++) {
      a0[r] = -(s0a[r] + s0b[r]);
      a1[r] = -(s1a[r] + s1b[r]);
      float mx = fmaxf(a0[r], a1[r]);
      mx = fmaxf(mx, __shfl_xor(mx, 1));
      mx = fmaxf(mx, __shfl_xor(mx, 2));
      mx = fmaxf(mx, __shfl_xor(mx, 4));
      mx = fmaxf(mx, __shfl_xor(mx, 8));
      tmax[r] = mx;
    }
    float d01 = fmaxf(tmax[0] - M[0], tmax[1] - M[1]);
    float d23 = fmaxf(tmax[2] - M[2], tmax[3] - M[3]);
    if (__any(fmaxf(d01, d23) > 3.0f)) {
      float scv[4];
#pragma unroll
      for (int r = 0; r < 4; r++) {
        float nm = fmaxf(M[r], tmax[r]);
        scv[r] = __expf(M[r] - nm);
        M[r] = nm;
      }
#pragma unroll
      for (int i = 0; i < 16; i++) {
#pragma unroll
        for (int r = 0; r < 4; r++) O[i][r] *= scv[r];
      }
#pragma unroll
      for (int r = 0; r < 4; r++) O17[r] *= scv[r];
    }
#pragma unroll
    for (int r = 0; r < 4; r++) {
      float p0 = __expf(a0[r] - M[r]);
      float p1 = __expf(a1[r] - M[r]);
      Plds[w][g * 4 + r][l15] = f2b(p0);
      Plds[w][g * 4 + r][16 + l15] = f2b(p1);
    }

    // V[t] ready: own 4 oldest loads drained; barrier syncs other waves' quarters
    if (t + 1 < t1) { asm volatile("s_waitcnt vmcnt(4)" ::: "memory"); }
    else            { asm volatile("s_waitcnt vmcnt(0)" ::: "memory"); }
    block_bar();

    bf16x8 pf = *reinterpret_cast<const bf16x8*>(&Plds[w][l15][g * 8]);
    __builtin_amdgcn_s_setprio(1);
#pragma unroll
    for (int cs = 0; cs < 16; ++cs) {
      bf16x8 vf = *reinterpret_cast<const bf16x8*>(&Vt[0] + ((size_t)cs * 64 + lane) * 8);
      O[cs] = __builtin_amdgcn_mfma_f32_16x16x32_bf16(pf, vf, O[cs], 0, 0, 0);
    }
    O17 = __builtin_amdgcn_mfma_f32_16x16x32_bf16(pf, onesf, O17, 0, 0, 0);
    __builtin_amdgcn_s_setprio(0);

    // K[t+1] complete for all waves; all waves done reading Vt
    asm volatile("s_waitcnt vmcnt(0)" ::: "memory");
    block_bar();
    cur ^= 1;
  }

  if (SPLIT) {
    // partials: Po[pb][c(256)][n(64)] bf16, Mv/Lv[pb][64]
    // row index within the 64-row Q tile = w*16 + g*4 + r  (w offset REQUIRED)
    int pb = bid;
    int nloc = w * 16 + g * 4;
#pragma unroll
    for (int cs = 0; cs < 16; cs++) {
      int c = cs * 16 + l15;
      ushort4 st;
      st.x = f2b(O[cs][0]); st.y = f2b(O[cs][1]);
      st.z = f2b(O[cs][2]); st.w = f2b(O[cs][3]);
      *reinterpret_cast<ushort4*>(Po + ((size_t)pb * 256 + c) * 64 + nloc) = st;
    }
    if (l15 == 0) {
#pragma unroll
      for (int r = 0; r < 4; r++) {
        Mv[(size_t)pb * 64 + nloc + r] = M[r];
        Lv[(size_t)pb * 64 + nloc + r] = O17[r];
      }
    }
  } else {
    float gm = gamma[0];
    float rl[4];
#pragma unroll
    for (int r = 0; r < 4; r++) rl[r] = gm / O17[r];
    size_t ob = (size_t)b * C1 * NSP + n0 + (size_t)g * 4;
#pragma unroll
    for (int cs = 0; cs < 16; cs++) {
      size_t idx = ob + (size_t)(cs * 16 + l15) * NSP;
      float4 x4 = *reinterpret_cast<const float4*>(&x1[idx]);
      float4 o4;
      o4.x = O[cs][0] * rl[0] + x4.x;
      o4.y = O[cs][1] * rl[1] + x4.y;
      o4.z = O[cs][2] * rl[2] + x4.z;
      o4.w = O[cs][3] * rl[3] + x4.w;
      *reinterpret_cast<float4*>(&out[idx]) = o4;
    }
  }
}

// ---- K5: combine the two KV halves ------------------------------------
__global__ __launch_bounds__(256) void k_comb(
    const ushort* __restrict__ Po, const float* __restrict__ Mv,
    const float* __restrict__ Lv, const float* __restrict__ x1,
    const float* __restrict__ gamma, float* __restrict__ out) {
  int bid = blockIdx.x;     // 8*49
  int b = bid & 7;
  int qt = bid >> 3;
  int tid = threadIdx.x;
  int n = tid & 63;
  int c0 = (tid >> 6) * 64;
  int pb0 = qt * 16 + b;
  int pb1 = qt * 16 + 8 + b;
  int n0 = qt * 64;
  float M0 = Mv[(size_t)pb0 * 64 + n], M1 = Mv[(size_t)pb1 * 64 + n];
  float L0 = Lv[(size_t)pb0 * 64 + n], L1 = Lv[(size_t)pb1 * 64 + n];
  float Ms = fmaxf(M0, M1);
  float w0 = __expf(M0 - Ms), w1 = __expf(M1 - Ms);
  float rl = gamma[0] / (w0 * L0 + w1 * L1);
  const ushort* p0 = Po + (size_t)pb0 * 16384 + n;
  const ushort* p1 = Po + (size_t)pb1 * 16384 + n;
#pragma unroll 4
  for (int c = c0; c < c0 + 64; ++c) {
    float o0 = b2f(p0[(size_t)c * 64]);
    float o1 = b2f(p1[(size_t)c * 64]);
    size_t idx = ((size_t)b * C1 + c) * NSP + n0 + n;
    out[idx] = (w0 * o0 + w1 * o1) * rl + x1[idx];
  }
}

extern "C" void kernel_launch(void* const* d_in, const int* in_sizes, int n_in,
                              void* d_out, int out_size, void* d_ws, size_t ws_size,
                              hipStream_t stream) {
  const float* x1 = (const float*)d_in[0];
  const float* x2 = (const float*)d_in[1];
  const float* W = (const float*)d_in[2];
  const float* bp = (const float*)d_in[3];
  const float* gamma = (const float*)d_in[4];
  float* out = (float*)d_out;

  char* ws = (char*)d_ws;
  ushort* Wf = (ushort*)(ws + 0);               // 16*16*512*2    =   262144
  ushort* x1t = (ushort*)(ws + 524288);         // 8*3136*256*2   = 12845056
  ushort* Kf = (ushort*)(ws + 13369344);        // 8*196*8*64*8*2 = 12845056
  ushort* Vf = (ushort*)(ws + 26214400);        // 8*98*16*64*8*2 = 12845056
  ushort* Po = (ushort*)(ws + 39059456);        // 784*256*64*2   = 25690112
  float* Mv = (float*)(ws + 64749568);          // 784*64*4       =   200704
  float* Lv = (float*)(ws + 64950272);          // 784*64*4       =   200704
                                                // split total      65150976
  // x2f lives in d_out (exact fit): dead after k_proj, before k_attn epilogue.
  ushort* x2f = (ushort*)d_out;                 // 8*196*16*512*2 = 25690112

  k_wtf<<<dim3(16), dim3(256), 0, stream>>>(W, Wf);
  k_x1t<<<dim3(98, 8, 8), dim3(256), 0, stream>>>(x1, x1t);
  k_x2f<<<dim3(98, 16, 8), dim3(256), 0, stream>>>(x2, x2f);
  k_proj<<<dim3(784), dim3(256), 0, stream>>>(Wf, x2f, bp, Kf, Vf);

  if (ws_size >= 65150976ULL) {
    k_attn<1><<<dim3(784), dim3(256), 0, stream>>>(x1t, Kf, Vf, x1, gamma, out,
                                                   Po, Mv, Lv);
    k_comb<<<dim3(392), dim3(256), 0, stream>>>(Po, Mv, Lv, x1, gamma, out);
  } else {
    k_attn<0><<<dim3(392), dim3(256), 0, stream>>>(x1t, Kf, Vf, x1, gamma, out,
                                                   Po, Mv, Lv);
  }
}